// Round 3
// baseline (59.991 us; speedup 1.0000x reference)
//
#include <hip/hip_runtime.h>

// SoftRank via per-column counting-sort + windowed exact sigmoid. Round 3:
// same algorithm as round 2 (1024 buckets, window = buckets k-1..k+1,
// omitted-term deficit <= 2^-16.9 each), restructured for cheap control flow:
//   - 256-thread blocks (4 waves), 4 elements/thread
//   - bucket scan = int4 local prefix + __shfl_up wave scan + 4 partials
//   - 5 barriers total (was 20+), no 1024-wide Hillis-Steele
// Kernel model: ~3-4K cyc/block, 128 blocks on 256 CUs -> ~1.5-2 us.

#define K_LOG2E 1442.6950408889634f  // 1000 * log2(e)

constexpr int Bdim = 8;
constexpr int Ndim = 1024;
constexpr int Cdim = 16;
constexpr int NB   = 1024;
constexpr float RANGE = 6.0f;
constexpr int THREADS = 256;

__global__ __launch_bounds__(THREADS)
void softrank_bucket3(const float* __restrict__ x, float* __restrict__ out) {
    __shared__ int   cnt[NB];
    __shared__ int   cum[NB];     // inclusive prefix
    __shared__ int   off[NB];     // scatter cursors (exclusive prefix)
    __shared__ float sv[Ndim];    // bucket-ordered scaled values
    __shared__ int   wpart[4];    // per-wave scan partials

    const int t    = threadIdx.x;
    const int w    = t >> 6;
    const int lane = t & 63;
    const int b = blockIdx.x >> 4;
    const int c = blockIdx.x & 15;

    const float* xb = x + b * (Ndim * Cdim) + c;

    // Load 4 elements per thread; bucketize.
    const float inv_w = (float)NB / (2.0f * RANGE * K_LOG2E);
    float v[4]; int k[4];
    #pragma unroll
    for (int u = 0; u < 4; ++u) {
        const int e = t + THREADS * u;
        v[u] = K_LOG2E * xb[e * Cdim];
        int kk = (int)floorf((v[u] + RANGE * K_LOG2E) * inv_w);
        k[u] = min(max(kk, 0), NB - 1);
    }

    // Histogram.
    ((int4*)cnt)[t] = make_int4(0, 0, 0, 0);
    __syncthreads();                                  // [1]
    #pragma unroll
    for (int u = 0; u < 4; ++u) atomicAdd(&cnt[k[u]], 1);
    __syncthreads();                                  // [2]

    // Prefix sum: 4 buckets/thread local prefix -> wave shfl-scan -> partials.
    int4 c4 = ((const int4*)cnt)[t];
    int s0 = c4.x, s1 = s0 + c4.y, s2 = s1 + c4.z, s3 = s2 + c4.w;
    int ws = s3;
    #pragma unroll
    for (int d = 1; d < 64; d <<= 1) {
        int n = __shfl_up(ws, d, 64);
        if (lane >= d) ws += n;
    }
    const int wexcl = ws - s3;
    if (lane == 63) wpart[w] = ws;
    __syncthreads();                                  // [3]
    int base = wexcl;
    if (w > 0) base += wpart[0];
    if (w > 1) base += wpart[1];
    if (w > 2) base += wpart[2];
    ((int4*)cum)[t] = make_int4(base + s0, base + s1, base + s2, base + s3);
    ((int4*)off)[t] = make_int4(base, base + s0, base + s1, base + s2);
    __syncthreads();                                  // [4]

    // Scatter into bucket order.
    int pos[4];
    #pragma unroll
    for (int u = 0; u < 4; ++u) {
        pos[u] = atomicAdd(&off[k[u]], 1);
        sv[pos[u]] = v[u];
    }
    __syncthreads();                                  // [5]

    // Windowed exact sigmoid over buckets [k-1, k+1]; buckets <= k-2 are ~1.
    #pragma unroll
    for (int u = 0; u < 4; ++u) {
        const int lo = (k[u] >= 2) ? cum[k[u] - 2] : 0;
        const int hi = cum[min(k[u] + 1, NB - 1)];
        float acc = 0.0f;
        for (int p = lo; p < hi; ++p) {
            float d2 = v[u] - sv[p];                     // log2 units
            float e2 = __builtin_amdgcn_exp2f(-d2);
            acc += __builtin_amdgcn_rcpf(1.0f + e2);
        }
        const int e = t + THREADS * u;
        out[b * (Ndim * Cdim) + e * Cdim + c] =
            ((float)lo + acc) * (1.0f / (float)Ndim);
    }
}

extern "C" void kernel_launch(void* const* d_in, const int* in_sizes, int n_in,
                              void* d_out, int out_size, void* d_ws, size_t ws_size,
                              hipStream_t stream) {
    (void)in_sizes; (void)n_in; (void)d_ws; (void)ws_size; (void)out_size;
    const float* x = (const float*)d_in[0];
    float* out = (float*)d_out;
    softrank_bucket3<<<Bdim * Cdim, THREADS, 0, stream>>>(x, out);
}

// Round 4
// 57.364 us; speedup vs baseline: 1.0458x; 1.0458x over previous
//
#include <hip/hip_runtime.h>

// SoftRank via per-column counting-sort + windowed exact sigmoid. Round 4:
// identical algorithm to r2/r3 (1024 buckets over [-6,6), window = buckets
// k-1..k+1, omitted-term deficit <= 2^-16.9 each). Structure: 512-thread
// blocks (8 waves), 2 elements/thread -> 1024 waves total (2x r3 occupancy),
// 5 barriers, shfl-up wave scan + 8 partials. This is the lean limit of the
// algorithm; round exists to falsify the "harness-floor ~57us" hypothesis.

#define K_LOG2E 1442.6950408889634f  // 1000 * log2(e)

constexpr int Bdim = 8;
constexpr int Ndim = 1024;
constexpr int Cdim = 16;
constexpr int NB   = 1024;
constexpr float RANGE = 6.0f;
constexpr int THREADS = 512;
constexpr int U = Ndim / THREADS;    // 2 elements per thread

__global__ __launch_bounds__(THREADS)
void softrank_bucket4(const float* __restrict__ x, float* __restrict__ out) {
    __shared__ int   cnt[NB];
    __shared__ int   cum[NB];     // inclusive prefix
    __shared__ int   off[NB];     // scatter cursors (exclusive prefix)
    __shared__ float sv[Ndim];    // bucket-ordered scaled values
    __shared__ int   wpart[THREADS / 64];

    const int t    = threadIdx.x;
    const int w    = t >> 6;
    const int lane = t & 63;
    const int b = blockIdx.x >> 4;
    const int c = blockIdx.x & 15;

    const float* xb = x + b * (Ndim * Cdim) + c;

    // Load U elements per thread; bucketize.
    const float inv_w = (float)NB / (2.0f * RANGE * K_LOG2E);
    float v[U]; int k[U];
    #pragma unroll
    for (int u = 0; u < U; ++u) {
        const int e = t + THREADS * u;
        v[u] = K_LOG2E * xb[e * Cdim];
        int kk = (int)floorf((v[u] + RANGE * K_LOG2E) * inv_w);
        k[u] = min(max(kk, 0), NB - 1);
    }

    // Histogram.
    ((int2*)cnt)[t] = make_int2(0, 0);
    __syncthreads();                                  // [1]
    #pragma unroll
    for (int u = 0; u < U; ++u) atomicAdd(&cnt[k[u]], 1);
    __syncthreads();                                  // [2]

    // Prefix sum: 2 buckets/thread local prefix -> wave shfl-scan -> partials.
    int2 c2 = ((const int2*)cnt)[t];
    int s0 = c2.x, s1 = s0 + c2.y;
    int ws = s1;
    #pragma unroll
    for (int d = 1; d < 64; d <<= 1) {
        int n = __shfl_up(ws, d, 64);
        if (lane >= d) ws += n;
    }
    const int wexcl = ws - s1;
    if (lane == 63) wpart[w] = ws;
    __syncthreads();                                  // [3]
    int base = wexcl;
    #pragma unroll
    for (int q = 0; q < THREADS / 64; ++q)
        if (w > q) base += wpart[q];
    ((int2*)cum)[t] = make_int2(base + s0, base + s1);
    ((int2*)off)[t] = make_int2(base, base + s0);
    __syncthreads();                                  // [4]

    // Scatter into bucket order.
    #pragma unroll
    for (int u = 0; u < U; ++u) {
        int pos = atomicAdd(&off[k[u]], 1);
        sv[pos] = v[u];
    }
    __syncthreads();                                  // [5]

    // Windowed exact sigmoid over buckets [k-1, k+1]; buckets <= k-2 are ~1.
    #pragma unroll
    for (int u = 0; u < U; ++u) {
        const int lo = (k[u] >= 2) ? cum[k[u] - 2] : 0;
        const int hi = cum[min(k[u] + 1, NB - 1)];
        float acc = 0.0f;
        for (int p = lo; p < hi; ++p) {
            float d2 = v[u] - sv[p];                     // log2 units
            float e2 = __builtin_amdgcn_exp2f(-d2);
            acc += __builtin_amdgcn_rcpf(1.0f + e2);
        }
        const int e = t + THREADS * u;
        out[b * (Ndim * Cdim) + e * Cdim + c] =
            ((float)lo + acc) * (1.0f / (float)Ndim);
    }
}

extern "C" void kernel_launch(void* const* d_in, const int* in_sizes, int n_in,
                              void* d_out, int out_size, void* d_ws, size_t ws_size,
                              hipStream_t stream) {
    (void)in_sizes; (void)n_in; (void)d_ws; (void)ws_size; (void)out_size;
    const float* x = (const float*)d_in[0];
    float* out = (float*)d_out;
    softrank_bucket4<<<Bdim * Cdim, THREADS, 0, stream>>>(x, out);
}